// Round 8
// baseline (527.786 us; speedup 1.0000x reference)
//
#include <hip/hip_runtime.h>
#include <math.h>

#define T_ 128

// ws offsets (floats)
#define OFF_M2      0         // [256][256]
#define OFF_WCOMBT  65536     // [128][1280]
#define OFF_BIAS    229376    // [1280]
#define OFF_WCT     230656    // [256][128]
#define OFF_XG2     263424    // [128 t][32 b][1024 c]   (gate-major: c = gate*256+d)
#define OFF_BX2     4457728   // [128 t][32 b][256 d]
#define OFF_HSEQ    5506304   // [128 t][32 b][256 d]  (ht from LSTM chain)
#define OFF_HCSEQ   6554880   // [128 t][32 b][256 d]  (hn_partial from cfc chain)

#define SENTB 0xFFFFFFFFu

__device__ __forceinline__ float sigm_f(float x) { return 1.0f / (1.0f + __expf(-x)); }
__device__ __forceinline__ float tanh_f(float x) { return 1.0f - 2.0f / (__expf(2.0f * x) + 1.0f); }

__device__ __forceinline__ unsigned long long aload_u64(const unsigned long long* p) {
  return __hip_atomic_load(p, __ATOMIC_RELAXED, __HIP_MEMORY_SCOPE_AGENT);
}
__device__ __forceinline__ void astore_f(float* p, float v) {
  __hip_atomic_store(p, v, __ATOMIC_RELAXED, __HIP_MEMORY_SCOPE_AGENT);
}
__device__ __forceinline__ bool bad_u64(unsigned long long v) {
  return (unsigned)v == SENTB || (unsigned)(v >> 32) == SENTB;
}

// ---------------- pack: WcombT, bias, W_C^T ----------------
__global__ __launch_bounds__(256) void pack_kernel(
    const float* __restrict__ W_ih, const float* __restrict__ W_B,
    const float* __restrict__ b_ih, const float* __restrict__ b_hh,
    const float* __restrict__ b_B,  const float* __restrict__ W_C,
    float* __restrict__ ws) {
  int idx = blockIdx.x * 256 + threadIdx.x;
  if (idx < 163840) {  // WcombT[k][c]
    int k = idx / 1280, c = idx - k * 1280;
    ws[OFF_WCOMBT + idx] = (c < 1024) ? W_ih[c * 128 + k] : W_B[(c - 1024) * 128 + k];
    return;
  }
  idx -= 163840;
  if (idx < 1280) {
    ws[OFF_BIAS + idx] = (idx < 1024) ? (b_ih[idx] + b_hh[idx]) : b_B[idx - 1024];
    return;
  }
  idx -= 1280;
  if (idx < 32768) {  // W_CT[k][o]
    int k = idx >> 7, o = idx & 127;
    ws[OFF_WCT + idx] = W_C[o * 256 + k];
  }
}

// ---------------- M2 = (W_A D)(W_A D), D = diag(1/tau) ----------------
__global__ __launch_bounds__(256) void m2_kernel(
    const float* __restrict__ W_A, const float* __restrict__ tau,
    float* __restrict__ M2) {
  __shared__ float adrow[256];
  const int i = blockIdx.x, k = threadIdx.x;
  const float itk = 1.0f / tau[k];
  adrow[k] = W_A[i * 256 + k] * itk;
  __syncthreads();
  float s = 0.f;
#pragma unroll 8
  for (int m = 0; m < 256; ++m)
    s = fmaf(adrow[m], W_A[m * 256 + k], s);
  M2[i * 256 + k] = s * itk;
}

// ---------------- xg/Bx precompute, batch-major layout ----------------
__global__ __launch_bounds__(256) void xgt_kernel(
    const float* __restrict__ x, const float* __restrict__ WT,
    const float* __restrict__ bias, float* __restrict__ xg2,
    float* __restrict__ bx2) {
  __shared__ float xs[8 * 128];
  const int tid = threadIdx.x;
  const int rt = blockIdx.x, ct = blockIdx.y;
  ((float4*)xs)[tid] = ((const float4*)(x + rt * 1024))[tid];
  __syncthreads();
  const int r = tid >> 5, cg = tid & 31;
  const int c0 = ct * 256 + cg * 8;
  const float4* b4 = (const float4*)(bias + c0);
  float4 bA = b4[0], bB = b4[1];
  float a[8] = {bA.x, bA.y, bA.z, bA.w, bB.x, bB.y, bB.z, bB.w};
  const float4* xr4 = (const float4*)(xs + r * 128);
#pragma unroll 4
  for (int k4 = 0; k4 < 32; ++k4) {
    float4 xv = xr4[k4];
#define STEPB(kk, comp)                                                      \
    {                                                                        \
      const float4* w = (const float4*)(WT + (k4 * 4 + kk) * 1280 + c0);     \
      float4 wA = w[0], wB = w[1];                                           \
      a[0] = fmaf(wA.x, comp, a[0]); a[1] = fmaf(wA.y, comp, a[1]);          \
      a[2] = fmaf(wA.z, comp, a[2]); a[3] = fmaf(wA.w, comp, a[3]);          \
      a[4] = fmaf(wB.x, comp, a[4]); a[5] = fmaf(wB.y, comp, a[5]);          \
      a[6] = fmaf(wB.z, comp, a[6]); a[7] = fmaf(wB.w, comp, a[7]);          \
    }
    STEPB(0, xv.x) STEPB(1, xv.y) STEPB(2, xv.z) STEPB(3, xv.w)
#undef STEPB
  }
  const int row = rt * 8 + r;          // = b*128 + t
  const int b = row >> 7, t = row & 127;
  if (ct < 4) {
    float* dst = xg2 + (size_t)(t * 32 + b) * 1024 + ct * 256 + cg * 8;
#pragma unroll
    for (int i = 0; i < 8; ++i) dst[i] = a[i];
  } else {
    float* dst = bx2 + (size_t)(t * 32 + b) * 256 + cg * 8;
#pragma unroll
    for (int i = 0; i < 8; ++i) dst[i] = a[i];
  }
}

// ---------------- recurrence, batch-partitioned: 512 blocks ----------------
// blocks [0,256): LSTM, b = bix>>3, cb = bix&7, owns dims [32cb, 32cb+32)
// blocks [256,512): cfc, same mapping. Fan-in 8 (own batch peers only).
// Single barrier per step; in-wave shuffle reductions; double-buffered LDS.
// cfc stores hn_partial (no ht); consumers sum hcseq+hseq when staging.
__global__ __launch_bounds__(256) void recur_bp_kernel(
    const float* __restrict__ ts_all, const float* __restrict__ tau,
    const float* __restrict__ sigma, const float* __restrict__ W_hh,
    const float* __restrict__ W_A, const float* __restrict__ M2,
    const float* __restrict__ xg2, const float* __restrict__ bx2,
    float* __restrict__ hseq, float* __restrict__ hcseq) {
  const int tid = threadIdx.x;
  const int lane = tid & 63, w = tid >> 6;
  const unsigned long long* hsq  = (const unsigned long long*)hseq;
  const unsigned long long* hcsq = (const unsigned long long*)hcseq;

  __shared__ float h_s[2][256];   // staged state (h or true hc), double-buffered
  __shared__ float q_s[2][768];   // cfc q vector, double-buffered

  if (blockIdx.x < 256) {
    // ===================== LSTM (batch b, dims 32cb..) =====================
    const int b = blockIdx.x >> 3, cb = blockIdx.x & 7;
    // lane -> pair p (gate gt, dim jj within wave's 8), k-half kh
    const int p = lane >> 1, kh = lane & 1;
    const int gt = p >> 3, jj = p & 7;
    const int grow = gt * 256 + cb * 32 + 8 * w + jj;
    float4 wq[32];
    {
      const float4* src = (const float4*)(W_hh + grow * 256 + kh * 128);
#pragma unroll
      for (int k4 = 0; k4 < 32; ++k4) wq[k4] = src[k4];
    }
    float c_reg = 0.f;
    const int dcol = cb * 32 + 8 * w + lane;   // finalize lanes (lane<8) own dim dcol

    for (int t = 0; t < T_; ++t) {
      const int buf = t & 1;
      // prefetch xg for finalize lanes (independent of poll -> overlaps latency)
      float xgi = 0.f, xgf = 0.f, xgg = 0.f, xgo = 0.f;
      if (lane < 8) {
        const float* xp = xg2 + (size_t)(t * 32 + b) * 1024 + dcol;
        xgi = xp[0]; xgf = xp[256]; xgg = xp[512]; xgo = xp[768];
      }
      if (t == 0) {
        if (tid < 128) ((float2*)h_s[0])[tid] = make_float2(0.f, 0.f);
      } else if (tid < 128) {
        const unsigned long long* pp = hsq + (size_t)((t - 1) * 32 + b) * 128 + tid;
        unsigned long long v = aload_u64(pp);
        int spins = 0;
        while (bad_u64(v)) {
          if (++spins > 16) __builtin_amdgcn_s_sleep(1);
          v = aload_u64(pp);
        }
        union { unsigned long long u; float2 f; } H; H.u = v;
        ((float2*)h_s[buf])[tid] = H.f;
      }
      __syncthreads();   // the ONLY barrier per step

      // matvec: each lane one (gate,dim) half-dot; h broadcast in 2-addr groups
      const float4* h4 = (const float4*)(&h_s[buf][0] + kh * 128);
      float s = 0.f;
#pragma unroll
      for (int k4 = 0; k4 < 32; ++k4) {
        const float4 wv = wq[k4], hv = h4[k4];
        s = fmaf(wv.x, hv.x, s); s = fmaf(wv.y, hv.y, s);
        s = fmaf(wv.z, hv.z, s); s = fmaf(wv.w, hv.w, s);
      }
      s += __shfl_xor(s, 1);                 // merge k-halves (pair lanes)
      // gather this dim's 4 gates (intra-wave): pair p=gt*8+jj at lanes 2p
      const float gi = __shfl(s, 2 * lane);
      const float gf = __shfl(s, 2 * lane + 16);
      const float gg = __shfl(s, 2 * lane + 32);
      const float go = __shfl(s, 2 * lane + 48);
      if (lane < 8) {
        const float i_ = sigm_f(gi + xgi);
        const float f_ = sigm_f(gf + xgf);
        const float g_ = tanh_f(gg + xgg);
        const float o_ = sigm_f(go + xgo);
        c_reg = fmaf(f_, c_reg, i_ * g_);
        const float ht = o_ * tanh_f(c_reg);
        astore_f(hseq + (size_t)(t * 32 + b) * 256 + dcol, ht);  // 32B/wave
      }
    }
  } else {
    // ===================== cfc (batch b, rows 32cb..) =====================
    const int bix = blockIdx.x - 256;
    const int b = bix >> 3, cb = bix & 7;
    // lane -> row r (8 per wave), k-chunk kq8 (8 chunks of 96)
    const int r = 8 * w + (lane >> 3), kq8 = lane & 7;
    const int ci = cb * 32 + r;
    const float it_i = 1.0f / tau[ci];
    float4 wcf[24];
#pragma unroll
    for (int i4 = 0; i4 < 24; ++i4) {
      float v[4];
#pragma unroll
      for (int e = 0; e < 4; ++e) {
        const int kp = kq8 * 96 + i4 * 4 + e;
        if (kp < 256)      v[e] = W_A[ci * 256 + kp] / tau[kp];
        else if (kp < 512) v[e] = W_A[ci * 256 + (kp - 256)] * it_i;
        else               v[e] = 0.5f * M2[ci * 256 + (kp - 512)];
      }
      wcf[i4] = make_float4(v[0], v[1], v[2], v[3]);
    }
    float2 isg2 = make_float2(0.f, 0.f);
    if (tid < 128) isg2 = make_float2(1.0f / sigma[2 * tid], 1.0f / sigma[2 * tid + 1]);
    const bool fin = (kq8 == 0);

    for (int t = 0; t < T_; ++t) {
      const int buf = t & 1;
      const float ts = ts_all[b * T_ + t];   // broadcast
      float bx_v = 0.f;
      if (fin) bx_v = bx2[(size_t)(t * 32 + b) * 256 + ci];

      if (t == 0) {
        if (tid < 128) {
          const float2 z = make_float2(0.f, 0.f);
          ((float2*)h_s[0])[tid] = z;
          float2* qrow = (float2*)q_s[0];
          qrow[tid] = z; qrow[128 + tid] = z; qrow[256 + tid] = z;
        }
      } else if (tid < 128) {
        // true hc(t-1) = hn_partial(t-1) + ht(t-1): poll BOTH in one flight
        const size_t base = (size_t)((t - 1) * 32 + b) * 128 + tid;
        const unsigned long long* pc = hcsq + base;
        const unsigned long long* ph = hsq + base;
        unsigned long long vc = aload_u64(pc);
        unsigned long long vh = aload_u64(ph);
        int spins = 0;
        while (bad_u64(vc) || bad_u64(vh)) {
          if (++spins > 16) __builtin_amdgcn_s_sleep(1);
          vc = aload_u64(pc);
          vh = aload_u64(ph);
        }
        union { unsigned long long u; float2 f; } C, H;
        C.u = vc; H.u = vh;
        const float2 hcv = make_float2(C.f.x + H.f.x, C.f.y + H.f.y);
        ((float2*)h_s[buf])[tid] = hcv;
        float2* qrow = (float2*)q_s[buf];
        qrow[tid]       = make_float2(ts * hcv.x, ts * hcv.y);
        qrow[128 + tid] = make_float2(ts * tanh_f(hcv.x * isg2.x),
                                      ts * tanh_f(hcv.y * isg2.y));
        qrow[256 + tid] = make_float2(ts * (ts * hcv.x), ts * (ts * hcv.y));
      }
      __syncthreads();   // the ONLY barrier per step

      // matvec: q broadcast float4 reads, weights in VGPRs
      const float4* q4 = (const float4*)q_s[buf];
      float s = 0.f;
#pragma unroll
      for (int i4 = 0; i4 < 24; ++i4) {
        const float4 wv = wcf[i4], qv = q4[kq8 * 24 + i4];
        s = fmaf(wv.x, qv.x, s); s = fmaf(wv.y, qv.y, s);
        s = fmaf(wv.z, qv.z, s); s = fmaf(wv.w, qv.w, s);
      }
      // reduce over the 8 k-chunks (lane low bits) in-wave
      s += __shfl_xor(s, 1); s += __shfl_xor(s, 2); s += __shfl_xor(s, 4);
      if (fin) {
        const float hc_own = h_s[buf][ci];
        const float hn_p = hc_own + s + ts * bx_v * it_i;
        astore_f(hcseq + (size_t)(t * 32 + b) * 256 + ci, hn_p);  // 32B/wave
      }
    }
  }
}

// ---------------- y = (hc_partial + ht) @ W_C^T + b_C ----------------
__global__ __launch_bounds__(256) void out_kernel(
    const float* __restrict__ hc, const float* __restrict__ ht,
    const float* __restrict__ WCT, const float* __restrict__ bC,
    float* __restrict__ y) {
  __shared__ float hs[16 * 256];
  const int tid = threadIdx.x;
#pragma unroll
  for (int v = 0; v < 4; ++v) {
    const int flat = v * 256 + tid;
    const int r = flat >> 6, f4 = flat & 63;
    const int row = blockIdx.x * 16 + r;   // = b*128 + t
    const int b = row >> 7, t = row & 127;
    const float4 a = ((const float4*)(hc + (size_t)(t * 32 + b) * 256))[f4];
    const float4 h = ((const float4*)(ht + (size_t)(t * 32 + b) * 256))[f4];
    ((float4*)hs)[flat] = make_float4(a.x + h.x, a.y + h.y, a.z + h.z, a.w + h.w);
  }
  __syncthreads();
  const int r = tid >> 4, cgg = tid & 15;
  const int c0 = cgg * 8;
  const float4* b4 = (const float4*)(bC + c0);
  float4 bA = b4[0], bB = b4[1];
  float a0 = bA.x, a1 = bA.y, a2 = bA.z, a3 = bA.w;
  float a4 = bB.x, a5 = bB.y, a6 = bB.z, a7 = bB.w;
  const float4* hr4 = (const float4*)(hs + r * 256);
#pragma unroll 4
  for (int k4 = 0; k4 < 64; ++k4) {
    float4 hv = hr4[k4];
#define STEPD(kk, comp)                                                     \
    {                                                                       \
      const float4* w = (const float4*)(WCT + (k4 * 4 + kk) * 128 + c0);    \
      float4 wA = w[0], wB = w[1];                                          \
      a0 = fmaf(wA.x, comp, a0); a1 = fmaf(wA.y, comp, a1);                 \
      a2 = fmaf(wA.z, comp, a2); a3 = fmaf(wA.w, comp, a3);                 \
      a4 = fmaf(wB.x, comp, a4); a5 = fmaf(wB.y, comp, a5);                 \
      a6 = fmaf(wB.z, comp, a6); a7 = fmaf(wB.w, comp, a7);                 \
    }
    STEPD(0, hv.x) STEPD(1, hv.y) STEPD(2, hv.z) STEPD(3, hv.w)
#undef STEPD
  }
  const int row = blockIdx.x * 16 + r;
  float4* dst = (float4*)(y + (size_t)row * 128 + c0);
  dst[0] = make_float4(a0, a1, a2, a3);
  dst[1] = make_float4(a4, a5, a6, a7);
}

extern "C" void kernel_launch(void* const* d_in, const int* in_sizes, int n_in,
                              void* d_out, int out_size, void* d_ws, size_t ws_size,
                              hipStream_t stream) {
  const float* x     = (const float*)d_in[0];
  const float* tspan = (const float*)d_in[1];
  const float* tau   = (const float*)d_in[2];
  const float* sigma = (const float*)d_in[3];
  const float* W_A   = (const float*)d_in[4];
  const float* W_B   = (const float*)d_in[5];
  const float* b_B   = (const float*)d_in[6];
  const float* W_C   = (const float*)d_in[7];
  const float* b_C   = (const float*)d_in[8];
  const float* W_ih  = (const float*)d_in[9];
  const float* W_hh  = (const float*)d_in[10];
  const float* b_ih  = (const float*)d_in[11];
  const float* b_hh  = (const float*)d_in[12];
  float* ws = (float*)d_ws;
  float* y = (float*)d_out;

  // sentinel-fill hseq+hcseq (0xFF bytes == SENTB dwords), 8 MB
  (void)hipMemsetAsync(ws + OFF_HSEQ, 0xFF, (size_t)2 * 1048576 * sizeof(float), stream);
  pack_kernel<<<774, 256, 0, stream>>>(W_ih, W_B, b_ih, b_hh, b_B, W_C, ws);
  m2_kernel<<<256, 256, 0, stream>>>(W_A, tau, ws + OFF_M2);
  xgt_kernel<<<dim3(512, 5), 256, 0, stream>>>(x, ws + OFF_WCOMBT, ws + OFF_BIAS,
                                               ws + OFF_XG2, ws + OFF_BX2);
  recur_bp_kernel<<<512, 256, 0, stream>>>(
      tspan, tau, sigma, W_hh, W_A, ws + OFF_M2, ws + OFF_XG2, ws + OFF_BX2,
      ws + OFF_HSEQ, ws + OFF_HCSEQ);
  out_kernel<<<256, 256, 0, stream>>>(ws + OFF_HCSEQ, ws + OFF_HSEQ,
                                      ws + OFF_WCT, b_C, y);
}

// Round 9
// 428.280 us; speedup vs baseline: 1.2323x; 1.2323x over previous
//
#include <hip/hip_runtime.h>
#include <math.h>

#define T_ 128

// ws offsets (floats)
#define OFF_M2      0         // [256][256]
#define OFF_WCOMBT  65536     // [128][1280]
#define OFF_BIAS    229376    // [1280]
#define OFF_WCT     230656    // [256][128]
#define OFF_XG2     263424    // [128 t][32 b][1024 c]   (gate-major: c = gate*256+d)
#define OFF_BX2     4457728   // [128 t][32 b][256 d]
#define OFF_HSEQ    5506304   // [128 t][32 b][256 d]  (ht from LSTM chain)
#define OFF_HCSEQ   6554880   // [128 t][32 b][256 d]  (hn_partial from cfc chain)

#define SENTB 0xFFFFFFFFu

__device__ __forceinline__ float sigm_f(float x) { return 1.0f / (1.0f + __expf(-x)); }
__device__ __forceinline__ float tanh_f(float x) { return 1.0f - 2.0f / (__expf(2.0f * x) + 1.0f); }

__device__ __forceinline__ unsigned long long aload_u64(const unsigned long long* p) {
  return __hip_atomic_load(p, __ATOMIC_RELAXED, __HIP_MEMORY_SCOPE_AGENT);
}
__device__ __forceinline__ void astore_f(float* p, float v) {
  __hip_atomic_store(p, v, __ATOMIC_RELAXED, __HIP_MEMORY_SCOPE_AGENT);
}
__device__ __forceinline__ bool bad_u64(unsigned long long v) {
  return (unsigned)v == SENTB || (unsigned)(v >> 32) == SENTB;
}

// ---------------- pack: WcombT, bias, W_C^T ----------------
__global__ __launch_bounds__(256) void pack_kernel(
    const float* __restrict__ W_ih, const float* __restrict__ W_B,
    const float* __restrict__ b_ih, const float* __restrict__ b_hh,
    const float* __restrict__ b_B,  const float* __restrict__ W_C,
    float* __restrict__ ws) {
  int idx = blockIdx.x * 256 + threadIdx.x;
  if (idx < 163840) {  // WcombT[k][c]
    int k = idx / 1280, c = idx - k * 1280;
    ws[OFF_WCOMBT + idx] = (c < 1024) ? W_ih[c * 128 + k] : W_B[(c - 1024) * 128 + k];
    return;
  }
  idx -= 163840;
  if (idx < 1280) {
    ws[OFF_BIAS + idx] = (idx < 1024) ? (b_ih[idx] + b_hh[idx]) : b_B[idx - 1024];
    return;
  }
  idx -= 1280;
  if (idx < 32768) {  // W_CT[k][o]
    int k = idx >> 7, o = idx & 127;
    ws[OFF_WCT + idx] = W_C[o * 256 + k];
  }
}

// ---------------- M2 = (W_A D)(W_A D), D = diag(1/tau) ----------------
__global__ __launch_bounds__(256) void m2_kernel(
    const float* __restrict__ W_A, const float* __restrict__ tau,
    float* __restrict__ M2) {
  __shared__ float adrow[256];
  const int i = blockIdx.x, k = threadIdx.x;
  const float itk = 1.0f / tau[k];
  adrow[k] = W_A[i * 256 + k] * itk;
  __syncthreads();
  float s = 0.f;
#pragma unroll 8
  for (int m = 0; m < 256; ++m)
    s = fmaf(adrow[m], W_A[m * 256 + k], s);
  M2[i * 256 + k] = s * itk;
}

// ---------------- xg/Bx precompute, batch-major layout ----------------
__global__ __launch_bounds__(256) void xgt_kernel(
    const float* __restrict__ x, const float* __restrict__ WT,
    const float* __restrict__ bias, float* __restrict__ xg2,
    float* __restrict__ bx2) {
  __shared__ float xs[8 * 128];
  const int tid = threadIdx.x;
  const int rt = blockIdx.x, ct = blockIdx.y;
  ((float4*)xs)[tid] = ((const float4*)(x + rt * 1024))[tid];
  __syncthreads();
  const int r = tid >> 5, cg = tid & 31;
  const int c0 = ct * 256 + cg * 8;
  const float4* b4 = (const float4*)(bias + c0);
  float4 bA = b4[0], bB = b4[1];
  float a[8] = {bA.x, bA.y, bA.z, bA.w, bB.x, bB.y, bB.z, bB.w};
  const float4* xr4 = (const float4*)(xs + r * 128);
#pragma unroll 4
  for (int k4 = 0; k4 < 32; ++k4) {
    float4 xv = xr4[k4];
#define STEPB(kk, comp)                                                      \
    {                                                                        \
      const float4* w = (const float4*)(WT + (k4 * 4 + kk) * 1280 + c0);     \
      float4 wA = w[0], wB = w[1];                                           \
      a[0] = fmaf(wA.x, comp, a[0]); a[1] = fmaf(wA.y, comp, a[1]);          \
      a[2] = fmaf(wA.z, comp, a[2]); a[3] = fmaf(wA.w, comp, a[3]);          \
      a[4] = fmaf(wB.x, comp, a[4]); a[5] = fmaf(wB.y, comp, a[5]);          \
      a[6] = fmaf(wB.z, comp, a[6]); a[7] = fmaf(wB.w, comp, a[7]);          \
    }
    STEPB(0, xv.x) STEPB(1, xv.y) STEPB(2, xv.z) STEPB(3, xv.w)
#undef STEPB
  }
  const int row = rt * 8 + r;          // = b*128 + t
  const int b = row >> 7, t = row & 127;
  if (ct < 4) {
    float* dst = xg2 + (size_t)(t * 32 + b) * 1024 + ct * 256 + cg * 8;
#pragma unroll
    for (int i = 0; i < 8; ++i) dst[i] = a[i];
  } else {
    float* dst = bx2 + (size_t)(t * 32 + b) * 256 + cg * 8;
#pragma unroll
    for (int i = 0; i < 8; ++i) dst[i] = a[i];
  }
}

// ---------------- recurrence, batch-partitioned: 512 blocks ----------------
// blocks [0,256): LSTM, b = bix>>3, cb = bix&7, owns dims [32cb, 32cb+32)
// blocks [256,512): cfc, same mapping. Fan-in 8 (own batch peers only).
// Single barrier per step; in-wave shuffle reductions; double-buffered LDS.
// cfc k-chunks are INTERLEAVED (kp = 32*i4 + 4*kq8 + e) so the 8 per-instr
// LDS addresses are consecutive float4s -> all 32 banks, conflict-free.
__global__ __launch_bounds__(256) void recur_bp_kernel(
    const float* __restrict__ ts_all, const float* __restrict__ tau,
    const float* __restrict__ sigma, const float* __restrict__ W_hh,
    const float* __restrict__ W_A, const float* __restrict__ M2,
    const float* __restrict__ xg2, const float* __restrict__ bx2,
    float* __restrict__ hseq, float* __restrict__ hcseq) {
  const int tid = threadIdx.x;
  const int lane = tid & 63, w = tid >> 6;
  const unsigned long long* hsq  = (const unsigned long long*)hseq;
  const unsigned long long* hcsq = (const unsigned long long*)hcseq;

  __shared__ float h_s[2][256];   // staged state (h or true hc), double-buffered
  __shared__ float q_s[2][768];   // cfc q vector, double-buffered

  if (blockIdx.x < 256) {
    // ===================== LSTM (batch b, dims 32cb..) =====================
    const int b = blockIdx.x >> 3, cb = blockIdx.x & 7;
    // lane -> pair p (gate gt, dim jj within wave's 8), k-half kh
    const int p = lane >> 1, kh = lane & 1;
    const int gt = p >> 3, jj = p & 7;
    const int grow = gt * 256 + cb * 32 + 8 * w + jj;
    float4 wq[32];
    {
      const float4* src = (const float4*)(W_hh + grow * 256 + kh * 128);
#pragma unroll
      for (int k4 = 0; k4 < 32; ++k4) wq[k4] = src[k4];
    }
    float c_reg = 0.f;
    const int dcol = cb * 32 + 8 * w + lane;   // finalize lanes (lane<8) own dim dcol

    for (int t = 0; t < T_; ++t) {
      const int buf = t & 1;
      // prefetch xg for finalize lanes (independent of poll -> overlaps latency)
      float xgi = 0.f, xgf = 0.f, xgg = 0.f, xgo = 0.f;
      if (lane < 8) {
        const float* xp = xg2 + (size_t)(t * 32 + b) * 1024 + dcol;
        xgi = xp[0]; xgf = xp[256]; xgg = xp[512]; xgo = xp[768];
      }
      if (t == 0) {
        if (tid < 128) ((float2*)h_s[0])[tid] = make_float2(0.f, 0.f);
      } else if (tid < 128) {
        const unsigned long long* pp = hsq + (size_t)((t - 1) * 32 + b) * 128 + tid;
        unsigned long long v = aload_u64(pp);
        int spins = 0;
        while (bad_u64(v)) {
          if (++spins > 16) __builtin_amdgcn_s_sleep(1);
          v = aload_u64(pp);
        }
        union { unsigned long long u; float2 f; } H; H.u = v;
        ((float2*)h_s[buf])[tid] = H.f;
      }
      __syncthreads();   // the ONLY barrier per step

      // matvec: each lane one (gate,dim) half-dot; h broadcast in 2-addr groups
      const float4* h4 = (const float4*)(&h_s[buf][0] + kh * 128);
      float s = 0.f;
#pragma unroll
      for (int k4 = 0; k4 < 32; ++k4) {
        const float4 wv = wq[k4], hv = h4[k4];
        s = fmaf(wv.x, hv.x, s); s = fmaf(wv.y, hv.y, s);
        s = fmaf(wv.z, hv.z, s); s = fmaf(wv.w, hv.w, s);
      }
      s += __shfl_xor(s, 1);                 // merge k-halves (pair lanes)
      // gather this dim's 4 gates (intra-wave): pair p=gt*8+jj at lanes 2p
      const float gi = __shfl(s, 2 * lane);
      const float gf = __shfl(s, 2 * lane + 16);
      const float gg = __shfl(s, 2 * lane + 32);
      const float go = __shfl(s, 2 * lane + 48);
      if (lane < 8) {
        const float i_ = sigm_f(gi + xgi);
        const float f_ = sigm_f(gf + xgf);
        const float g_ = tanh_f(gg + xgg);
        const float o_ = sigm_f(go + xgo);
        c_reg = fmaf(f_, c_reg, i_ * g_);
        const float ht = o_ * tanh_f(c_reg);
        astore_f(hseq + (size_t)(t * 32 + b) * 256 + dcol, ht);  // 32B/wave
      }
    }
  } else {
    // ===================== cfc (batch b, rows 32cb..) =====================
    const int bix = blockIdx.x - 256;
    const int b = bix >> 3, cb = bix & 7;
    // lane -> row r (8 per wave), k-chunk kq8 in LOW 3 bits (for shfl reduce)
    const int r = 8 * w + (lane >> 3), kq8 = lane & 7;
    const int ci = cb * 32 + r;
    const float it_i = 1.0f / tau[ci];
    // INTERLEAVED k mapping: lane kq8 handles kp = 32*i4 + 4*kq8 + e
    float4 wcf[24];
#pragma unroll
    for (int i4 = 0; i4 < 24; ++i4) {
      float v[4];
#pragma unroll
      for (int e = 0; e < 4; ++e) {
        const int kp = 32 * i4 + 4 * kq8 + e;
        if (kp < 256)      v[e] = W_A[ci * 256 + kp] / tau[kp];
        else if (kp < 512) v[e] = W_A[ci * 256 + (kp - 256)] * it_i;
        else               v[e] = 0.5f * M2[ci * 256 + (kp - 512)];
      }
      wcf[i4] = make_float4(v[0], v[1], v[2], v[3]);
    }
    float2 isg2 = make_float2(0.f, 0.f);
    if (tid < 128) isg2 = make_float2(1.0f / sigma[2 * tid], 1.0f / sigma[2 * tid + 1]);
    const bool fin = (kq8 == 0);

    for (int t = 0; t < T_; ++t) {
      const int buf = t & 1;
      const float ts = ts_all[b * T_ + t];   // broadcast
      float bx_v = 0.f;
      if (fin) bx_v = bx2[(size_t)(t * 32 + b) * 256 + ci];

      if (t == 0) {
        if (tid < 128) {
          const float2 z = make_float2(0.f, 0.f);
          ((float2*)h_s[0])[tid] = z;
          float2* qrow = (float2*)q_s[0];
          qrow[tid] = z; qrow[128 + tid] = z; qrow[256 + tid] = z;
        }
      } else if (tid < 128) {
        // true hc(t-1) = hn_partial(t-1) + ht(t-1): poll BOTH in one flight
        const size_t base = (size_t)((t - 1) * 32 + b) * 128 + tid;
        const unsigned long long* pc = hcsq + base;
        const unsigned long long* ph = hsq + base;
        unsigned long long vc = aload_u64(pc);
        unsigned long long vh = aload_u64(ph);
        int spins = 0;
        while (bad_u64(vc) || bad_u64(vh)) {
          if (++spins > 16) __builtin_amdgcn_s_sleep(1);
          vc = aload_u64(pc);
          vh = aload_u64(ph);
        }
        union { unsigned long long u; float2 f; } C, H;
        C.u = vc; H.u = vh;
        const float2 hcv = make_float2(C.f.x + H.f.x, C.f.y + H.f.y);
        ((float2*)h_s[buf])[tid] = hcv;
        float2* qrow = (float2*)q_s[buf];
        qrow[tid]       = make_float2(ts * hcv.x, ts * hcv.y);
        qrow[128 + tid] = make_float2(ts * tanh_f(hcv.x * isg2.x),
                                      ts * tanh_f(hcv.y * isg2.y));
        qrow[256 + tid] = make_float2(ts * (ts * hcv.x), ts * (ts * hcv.y));
      }
      __syncthreads();   // the ONLY barrier per step

      // matvec: per instr the 8 kq8 lanes read 8 CONSECUTIVE float4s
      // (128B, all 32 banks, 8-lane broadcast each) -> conflict-free
      const float4* q4 = (const float4*)q_s[buf];
      float s = 0.f;
#pragma unroll
      for (int i4 = 0; i4 < 24; ++i4) {
        const float4 wv = wcf[i4], qv = q4[i4 * 8 + kq8];
        s = fmaf(wv.x, qv.x, s); s = fmaf(wv.y, qv.y, s);
        s = fmaf(wv.z, qv.z, s); s = fmaf(wv.w, qv.w, s);
      }
      // reduce over the 8 k-chunks (lane low bits) in-wave
      s += __shfl_xor(s, 1); s += __shfl_xor(s, 2); s += __shfl_xor(s, 4);
      if (fin) {
        const float hc_own = h_s[buf][ci];
        const float hn_p = hc_own + s + ts * bx_v * it_i;
        astore_f(hcseq + (size_t)(t * 32 + b) * 256 + ci, hn_p);  // 32B/wave
      }
    }
  }
}

// ---------------- y = (hc_partial + ht) @ W_C^T + b_C ----------------
__global__ __launch_bounds__(256) void out_kernel(
    const float* __restrict__ hc, const float* __restrict__ ht,
    const float* __restrict__ WCT, const float* __restrict__ bC,
    float* __restrict__ y) {
  __shared__ float hs[16 * 256];
  const int tid = threadIdx.x;
#pragma unroll
  for (int v = 0; v < 4; ++v) {
    const int flat = v * 256 + tid;
    const int r = flat >> 6, f4 = flat & 63;
    const int row = blockIdx.x * 16 + r;   // = b*128 + t
    const int b = row >> 7, t = row & 127;
    const float4 a = ((const float4*)(hc + (size_t)(t * 32 + b) * 256))[f4];
    const float4 h = ((const float4*)(ht + (size_t)(t * 32 + b) * 256))[f4];
    ((float4*)hs)[flat] = make_float4(a.x + h.x, a.y + h.y, a.z + h.z, a.w + h.w);
  }
  __syncthreads();
  const int r = tid >> 4, cgg = tid & 15;
  const int c0 = cgg * 8;
  const float4* b4 = (const float4*)(bC + c0);
  float4 bA = b4[0], bB = b4[1];
  float a0 = bA.x, a1 = bA.y, a2 = bA.z, a3 = bA.w;
  float a4 = bB.x, a5 = bB.y, a6 = bB.z, a7 = bB.w;
  const float4* hr4 = (const float4*)(hs + r * 256);
#pragma unroll 4
  for (int k4 = 0; k4 < 64; ++k4) {
    float4 hv = hr4[k4];
#define STEPD(kk, comp)                                                     \
    {                                                                       \
      const float4* w = (const float4*)(WCT + (k4 * 4 + kk) * 128 + c0);    \
      float4 wA = w[0], wB = w[1];                                          \
      a0 = fmaf(wA.x, comp, a0); a1 = fmaf(wA.y, comp, a1);                 \
      a2 = fmaf(wA.z, comp, a2); a3 = fmaf(wA.w, comp, a3);                 \
      a4 = fmaf(wB.x, comp, a4); a5 = fmaf(wB.y, comp, a5);                 \
      a6 = fmaf(wB.z, comp, a6); a7 = fmaf(wB.w, comp, a7);                 \
    }
    STEPD(0, hv.x) STEPD(1, hv.y) STEPD(2, hv.z) STEPD(3, hv.w)
#undef STEPD
  }
  const int row = blockIdx.x * 16 + r;
  float4* dst = (float4*)(y + (size_t)row * 128 + c0);
  dst[0] = make_float4(a0, a1, a2, a3);
  dst[1] = make_float4(a4, a5, a6, a7);
}

extern "C" void kernel_launch(void* const* d_in, const int* in_sizes, int n_in,
                              void* d_out, int out_size, void* d_ws, size_t ws_size,
                              hipStream_t stream) {
  const float* x     = (const float*)d_in[0];
  const float* tspan = (const float*)d_in[1];
  const float* tau   = (const float*)d_in[2];
  const float* sigma = (const float*)d_in[3];
  const float* W_A   = (const float*)d_in[4];
  const float* W_B   = (const float*)d_in[5];
  const float* b_B   = (const float*)d_in[6];
  const float* W_C   = (const float*)d_in[7];
  const float* b_C   = (const float*)d_in[8];
  const float* W_ih  = (const float*)d_in[9];
  const float* W_hh  = (const float*)d_in[10];
  const float* b_ih  = (const float*)d_in[11];
  const float* b_hh  = (const float*)d_in[12];
  float* ws = (float*)d_ws;
  float* y = (float*)d_out;

  // sentinel-fill hseq+hcseq (0xFF bytes == SENTB dwords), 8 MB
  (void)hipMemsetAsync(ws + OFF_HSEQ, 0xFF, (size_t)2 * 1048576 * sizeof(float), stream);
  pack_kernel<<<774, 256, 0, stream>>>(W_ih, W_B, b_ih, b_hh, b_B, W_C, ws);
  m2_kernel<<<256, 256, 0, stream>>>(W_A, tau, ws + OFF_M2);
  xgt_kernel<<<dim3(512, 5), 256, 0, stream>>>(x, ws + OFF_WCOMBT, ws + OFF_BIAS,
                                               ws + OFF_XG2, ws + OFF_BX2);
  recur_bp_kernel<<<512, 256, 0, stream>>>(
      tspan, tau, sigma, W_hh, W_A, ws + OFF_M2, ws + OFF_XG2, ws + OFF_BX2,
      ws + OFF_HSEQ, ws + OFF_HCSEQ);
  out_kernel<<<256, 256, 0, stream>>>(ws + OFF_HCSEQ, ws + OFF_HSEQ,
                                      ws + OFF_WCT, b_C, y);
}